// Round 7
// baseline (91.588 us; speedup 1.0000x reference)
//
#include <hip/hip_runtime.h>

// B=4, L=128, D=256, NUM_KNOTS=64, HEAD_DIM=4 -> N = 8192 knots/batch, 512 rows.
#define NQ 8192
#define BLROWS 512
#define DIM 256
#define KSLICES 16

// 0.5 (= 1/sqrt(4)) * log2(e): fold softmax scale + base-2 conversion into Q.
#define QSCALE 0.7213475204444817f

typedef float v2f __attribute__((ext_vector_type(2)));
typedef float v4f __attribute__((ext_vector_type(4)));

__device__ __forceinline__ float ex2(float x) {
#if __has_builtin(__builtin_amdgcn_exp2f)
    return __builtin_amdgcn_exp2f(x);
#else
    return exp2f(x);
#endif
}

// ---------------------------------------------------------------------------
// QKV projection: C[M,256] = (x[M,256] @ W^T) * scale. 4 rows/block.
// ---------------------------------------------------------------------------
__global__ __launch_bounds__(256) void qkv_proj(
    const float* __restrict__ x,
    const float* __restrict__ Wq, const float* __restrict__ Wk,
    const float* __restrict__ Wv,
    float* __restrict__ Qb, float* __restrict__ Kb, float* __restrict__ Vb)
{
    const int m = blockIdx.y;
    const float* W = (m == 0) ? Wq : (m == 1) ? Wk : Wv;
    float* C       = (m == 0) ? Qb : (m == 1) ? Kb : Vb;
    const float sc = (m == 0) ? QSCALE : 1.0f;
    const int j  = threadIdx.x;
    const int rb = blockIdx.x * 4;

    float acc[4] = {0.f, 0.f, 0.f, 0.f};
    const float4* __restrict__ W4 = reinterpret_cast<const float4*>(W + j * DIM);
    const float*  __restrict__ A0 = x + rb * DIM;

    #pragma unroll 4
    for (int d4 = 0; d4 < DIM / 4; ++d4) {
        const float4 w = W4[d4];
        #pragma unroll
        for (int r = 0; r < 4; ++r) {
            const float4 a = reinterpret_cast<const float4*>(A0 + r * DIM)[d4];
            acc[r] = fmaf(a.x, w.x, acc[r]);
            acc[r] = fmaf(a.y, w.y, acc[r]);
            acc[r] = fmaf(a.z, w.z, acc[r]);
            acc[r] = fmaf(a.w, w.w, acc[r]);
        }
    }
    #pragma unroll
    for (int r = 0; r < 4; ++r)
        C[(rb + r) * DIM + j] = acc[r] * sc;
}

// ---------------------------------------------------------------------------
// Attention partials. Grid (32 qt, 16 ks, 4 b) = 2048 blocks, 256 threads
// (4 waves). K/V staged in LDS in SoA layout (Kx/Ky/Kz/Kw, Vx/..): the
// key-quad inner loop reads each component as one wave-uniform ds_read_b128
// (4 keys), and all pk-math operands are natural {k_j, k_j+1} pairs —
// queries are splatted to {q,q} pairs ONCE outside the loop, so the inner
// loop has ZERO broadcast movs: per key per thread exactly 18 pk-slots
// (9 v_pk ops) + 4 exp. No-max softmax: p = exp2(s) (Q pre-scaled).
// Cross-wave reduction via 4 KB red2 buffer. P layout: P[b][ks][c][n].
// ---------------------------------------------------------------------------
__global__ __launch_bounds__(256, 4) void attn_partial(
    const float* __restrict__ Q, const float* __restrict__ K,
    const float* __restrict__ V, float* __restrict__ P)
{
    __shared__ __align__(16) float Ksoa[4][512];   // 8 KB
    __shared__ __align__(16) float Vsoa[4][512];   // 8 KB
    __shared__ float red2[4][256];                 // 4 KB

    const int t    = threadIdx.x;
    const int lane = t & 63;
    const int w    = __builtin_amdgcn_readfirstlane(t >> 6); // 0..3
    const int qt   = blockIdx.x;         // 0..31 (256 queries each)
    const int ks   = blockIdx.y;         // 0..15 (512 keys each)
    const int b    = blockIdx.z;         // 0..3

    // stage K/V slice with SoA transpose: thread t handles keys t and t+256
    {
        const float4* __restrict__ Kg = reinterpret_cast<const float4*>(K) + b * NQ + ks * 512;
        const float4* __restrict__ Vg = reinterpret_cast<const float4*>(V) + b * NQ + ks * 512;
        const float4 k0 = Kg[t], k1 = Kg[t + 256];
        const float4 v0 = Vg[t], v1 = Vg[t + 256];
        Ksoa[0][t] = k0.x; Ksoa[1][t] = k0.y; Ksoa[2][t] = k0.z; Ksoa[3][t] = k0.w;
        Ksoa[0][t + 256] = k1.x; Ksoa[1][t + 256] = k1.y; Ksoa[2][t + 256] = k1.z; Ksoa[3][t + 256] = k1.w;
        Vsoa[0][t] = v0.x; Vsoa[1][t] = v0.y; Vsoa[2][t] = v0.z; Vsoa[3][t] = v0.w;
        Vsoa[0][t + 256] = v1.x; Vsoa[1][t + 256] = v1.y; Vsoa[2][t + 256] = v1.z; Vsoa[3][t + 256] = v1.w;
    }

    // load Q and splat components into loop-invariant {q,q} pairs
    const float4* __restrict__ Qp = reinterpret_cast<const float4*>(Q) + b * NQ + qt * 256;
    v2f qx2[4], qy2[4], qz2[4], qw2[4];
    #pragma unroll
    for (int r = 0; r < 4; ++r) {
        const float4 q = Qp[r * 64 + lane];
        qx2[r] = v2f{q.x, q.x};
        qy2[r] = v2f{q.y, q.y};
        qz2[r] = v2f{q.z, q.z};
        qw2[r] = v2f{q.w, q.w};
    }
    v2f ls2[4], a02[4], a12[4], a22[4], a32[4];
    #pragma unroll
    for (int r = 0; r < 4; ++r) {
        ls2[r] = v2f{0.f, 0.f};
        a02[r] = v2f{0.f, 0.f}; a12[r] = v2f{0.f, 0.f};
        a22[r] = v2f{0.f, 0.f}; a32[r] = v2f{0.f, 0.f};
    }
    __syncthreads();

    const int kbase = w * 128;   // this wave's 128-key quarter

    #pragma unroll 2
    for (int jj = 0; jj < 32; ++jj) {
        const int j = kbase + jj * 4;
        // 8 wave-uniform ds_read_b128: 4 keys per component
        const v4f kx4 = *reinterpret_cast<const v4f*>(&Ksoa[0][j]);
        const v4f ky4 = *reinterpret_cast<const v4f*>(&Ksoa[1][j]);
        const v4f kz4 = *reinterpret_cast<const v4f*>(&Ksoa[2][j]);
        const v4f kw4 = *reinterpret_cast<const v4f*>(&Ksoa[3][j]);
        const v4f vx4 = *reinterpret_cast<const v4f*>(&Vsoa[0][j]);
        const v4f vy4 = *reinterpret_cast<const v4f*>(&Vsoa[1][j]);
        const v4f vz4 = *reinterpret_cast<const v4f*>(&Vsoa[2][j]);
        const v4f vw4 = *reinterpret_cast<const v4f*>(&Vsoa[3][j]);
        const v2f kxlo = __builtin_shufflevector(kx4, kx4, 0, 1), kxhi = __builtin_shufflevector(kx4, kx4, 2, 3);
        const v2f kylo = __builtin_shufflevector(ky4, ky4, 0, 1), kyhi = __builtin_shufflevector(ky4, ky4, 2, 3);
        const v2f kzlo = __builtin_shufflevector(kz4, kz4, 0, 1), kzhi = __builtin_shufflevector(kz4, kz4, 2, 3);
        const v2f kwlo = __builtin_shufflevector(kw4, kw4, 0, 1), kwhi = __builtin_shufflevector(kw4, kw4, 2, 3);
        const v2f vxlo = __builtin_shufflevector(vx4, vx4, 0, 1), vxhi = __builtin_shufflevector(vx4, vx4, 2, 3);
        const v2f vylo = __builtin_shufflevector(vy4, vy4, 0, 1), vyhi = __builtin_shufflevector(vy4, vy4, 2, 3);
        const v2f vzlo = __builtin_shufflevector(vz4, vz4, 0, 1), vzhi = __builtin_shufflevector(vz4, vz4, 2, 3);
        const v2f vwlo = __builtin_shufflevector(vw4, vw4, 0, 1), vwhi = __builtin_shufflevector(vw4, vw4, 2, 3);

        #pragma unroll
        for (int r = 0; r < 4; ++r) {
            v2f slo = kxlo * qx2[r];
            slo = __builtin_elementwise_fma(kylo, qy2[r], slo);
            slo = __builtin_elementwise_fma(kzlo, qz2[r], slo);
            slo = __builtin_elementwise_fma(kwlo, qw2[r], slo);
            v2f shi = kxhi * qx2[r];
            shi = __builtin_elementwise_fma(kyhi, qy2[r], shi);
            shi = __builtin_elementwise_fma(kzhi, qz2[r], shi);
            shi = __builtin_elementwise_fma(kwhi, qw2[r], shi);
            const v2f e01 = v2f{ex2(slo[0]), ex2(slo[1])};
            const v2f e23 = v2f{ex2(shi[0]), ex2(shi[1])};
            ls2[r] += e01;
            ls2[r] += e23;
            a02[r] = __builtin_elementwise_fma(e01, vxlo, a02[r]);
            a02[r] = __builtin_elementwise_fma(e23, vxhi, a02[r]);
            a12[r] = __builtin_elementwise_fma(e01, vylo, a12[r]);
            a12[r] = __builtin_elementwise_fma(e23, vyhi, a12[r]);
            a22[r] = __builtin_elementwise_fma(e01, vzlo, a22[r]);
            a22[r] = __builtin_elementwise_fma(e23, vzhi, a22[r]);
            a32[r] = __builtin_elementwise_fma(e01, vwlo, a32[r]);
            a32[r] = __builtin_elementwise_fma(e23, vwhi, a32[r]);
        }
    }

    // Per-component cross-wave reduction through the 4 KB red2 buffer.
    float* __restrict__ Pb = P + (size_t)((b * KSLICES + ks) * 5) * NQ + qt * 256;
    __syncthreads();

#define RED_ROUND(ARR, cidx)                                              \
    {                                                                     \
        _Pragma("unroll")                                                 \
        for (int r = 0; r < 4; ++r)                                       \
            red2[w][r * 64 + lane] = ARR[r][0] + ARR[r][1];               \
        __syncthreads();                                                  \
        Pb[(cidx) * NQ + t] =                                             \
            red2[0][t] + red2[1][t] + red2[2][t] + red2[3][t];            \
        __syncthreads();                                                  \
    }

    RED_ROUND(ls2, 0)
    RED_ROUND(a02, 1)
    RED_ROUND(a12, 2)
    RED_ROUND(a22, 3)
    RED_ROUND(a32, 4)
#undef RED_ROUND
}

// ---------------------------------------------------------------------------
// Fused merge + output projection. Grid 128 blocks x 256 thr; block = 4 rows
// = 256 knots. Phase 1: merge 16 key-slice partials, normalize, stash AO
// tile in LDS. Phase 2: out = AO @ Wo^T + bo.
// ---------------------------------------------------------------------------
__global__ __launch_bounds__(256) void merge_oproj(
    const float* __restrict__ P, const float* __restrict__ Wo,
    const float* __restrict__ bo, float* __restrict__ out)
{
    __shared__ float aoL[4][DIM];      // 4 KB

    const int rb = blockIdx.x * 4;     // first row (0..508)
    const int b  = rb >> 7;            // batch
    const int n0 = (rb & 127) * 64;    // first knot within batch
    const int t  = threadIdx.x;        // knot offset 0..255

    {
        float sums[5] = {0.f, 0.f, 0.f, 0.f, 0.f};
        const float* __restrict__ Pb = P + (size_t)(b * KSLICES * 5) * NQ + n0 + t;
        #pragma unroll
        for (int s = 0; s < KSLICES; ++s) {
            #pragma unroll
            for (int c = 0; c < 5; ++c)
                sums[c] += Pb[(s * 5 + c) * NQ];
        }
        const float inv = 1.0f / sums[0];
        const int row = t >> 6;
        const int d0  = (t & 63) * 4;
        aoL[row][d0 + 0] = sums[1] * inv;
        aoL[row][d0 + 1] = sums[2] * inv;
        aoL[row][d0 + 2] = sums[3] * inv;
        aoL[row][d0 + 3] = sums[4] * inv;
    }
    __syncthreads();

    const int j = t;
    float acc[4] = {0.f, 0.f, 0.f, 0.f};
    const float4* __restrict__ W4 = reinterpret_cast<const float4*>(Wo + j * DIM);
    #pragma unroll 4
    for (int d4 = 0; d4 < DIM / 4; ++d4) {
        const float4 wv = W4[d4];
        #pragma unroll
        for (int r = 0; r < 4; ++r) {
            const float4 a = reinterpret_cast<const float4*>(&aoL[r][0])[d4];
            acc[r] = fmaf(a.x, wv.x, acc[r]);
            acc[r] = fmaf(a.y, wv.y, acc[r]);
            acc[r] = fmaf(a.z, wv.z, acc[r]);
            acc[r] = fmaf(a.w, wv.w, acc[r]);
        }
    }
    const float bias = bo[j];
    #pragma unroll
    for (int r = 0; r < 4; ++r)
        out[(rb + r) * DIM + j] = acc[r] + bias;
}

extern "C" void kernel_launch(void* const* d_in, const int* in_sizes, int n_in,
                              void* d_out, int out_size, void* d_ws, size_t ws_size,
                              hipStream_t stream) {
    const float* x  = (const float*)d_in[0];
    const float* Wq = (const float*)d_in[1];
    const float* Wk = (const float*)d_in[2];
    const float* Wv = (const float*)d_in[3];
    const float* Wo = (const float*)d_in[4];
    const float* bo = (const float*)d_in[5];
    float* out = (float*)d_out;

    float* Qb = (float*)d_ws;              // 131072 f32
    float* Kb = Qb + BLROWS * DIM;         // 131072
    float* Vb = Kb + BLROWS * DIM;         // 131072
    float* P  = Vb + BLROWS * DIM;         // 4*16*5*8192 = 2,621,440 f32
    // total = 3,014,656 floats = 12.06 MB

    qkv_proj<<<dim3(128, 3), 256, 0, stream>>>(x, Wq, Wk, Wv, Qb, Kb, Vb);
    attn_partial<<<dim3(32, KSLICES, 4), 256, 0, stream>>>(Qb, Kb, Vb, P);
    merge_oproj<<<128, 256, 0, stream>>>(P, Wo, bo, out);
}